// Round 1
// baseline (762.767 us; speedup 1.0000x reference)
//
#include <hip/hip_runtime.h>

#define N_NODES 50000
#define N_EDGES 600000
#define IN_DIM  256
#define HID     128
#define BN_EPS  1e-5f

// ---------------------------------------------------------------------------
// init: deg[i] = 1.0 (self-loop contribution), colsum/colsumsq (256 floats) = 0
// ---------------------------------------------------------------------------
__global__ __launch_bounds__(256) void init_kernel(float* deg, float* colstats, int n) {
    int i = blockIdx.x * 256 + threadIdx.x;
    if (i < n) deg[i] = 1.0f;
    if (i < 256) colstats[i] = 0.0f;
}

// deg[col[e]] += 1 for each real edge
__global__ __launch_bounds__(256) void deg_kernel(const int* __restrict__ col, float* deg, int E) {
    int i = blockIdx.x * 256 + threadIdx.x;
    if (i < E) atomicAdd(&deg[col[i]], 1.0f);
}

// deg -> deg^{-1/2}  (deg >= 1 always, self-loops included)
__global__ __launch_bounds__(256) void rsqrt_kernel(float* deg, int n) {
    int i = blockIdx.x * 256 + threadIdx.x;
    if (i < n) deg[i] = rsqrtf(deg[i]);
}

// ---------------------------------------------------------------------------
// GEMM: h[M,128] = x[M,256] @ W[256,128], fp32 vector ALU.
// Tile: BM=64 rows x 128 cols, BK=32. 256 threads; each thread 8x4 accs.
// ---------------------------------------------------------------------------
#define BM 64
#define BK 32

__global__ __launch_bounds__(256) void gemm_kernel(const float* __restrict__ x,
                                                   const float* __restrict__ W,
                                                   float* __restrict__ h, int M) {
    __shared__ float xs[BK][BM];   // x tile, transposed (k-major)
    __shared__ float ws[BK][HID];  // W tile
    const int t = threadIdx.x;
    const int row0 = blockIdx.x * BM;
    const int tx = t & 31;   // col group: cols tx*4 .. tx*4+3
    const int ty = t >> 5;   // row group: rows ty*8 .. ty*8+7

    float acc[8][4];
    #pragma unroll
    for (int i = 0; i < 8; i++)
        #pragma unroll
        for (int j = 0; j < 4; j++) acc[i][j] = 0.0f;

    for (int k0 = 0; k0 < IN_DIM; k0 += BK) {
        // stage x tile: 64 rows x 32 k = 512 float4s, 2 per thread
        #pragma unroll
        for (int l = 0; l < 2; l++) {
            int q = t + l * 256;
            int r = q >> 3, kq = q & 7;           // 8 float4s per row
            int gr = row0 + r;
            float4 v = make_float4(0.f, 0.f, 0.f, 0.f);
            if (gr < M) v = *(const float4*)(x + (size_t)gr * IN_DIM + k0 + kq * 4);
            xs[kq * 4 + 0][r] = v.x;
            xs[kq * 4 + 1][r] = v.y;
            xs[kq * 4 + 2][r] = v.z;
            xs[kq * 4 + 3][r] = v.w;
        }
        // stage W tile: 32 k x 128 n = 1024 float4s, 4 per thread
        #pragma unroll
        for (int l = 0; l < 4; l++) {
            int q = t + l * 256;
            int kk = q >> 5, c4 = q & 31;
            *(float4*)(&ws[kk][c4 * 4]) = *(const float4*)(W + (size_t)(k0 + kk) * HID + c4 * 4);
        }
        __syncthreads();

        #pragma unroll
        for (int kk = 0; kk < BK; kk++) {
            float4 a0 = *(const float4*)(&xs[kk][ty * 8]);
            float4 a1 = *(const float4*)(&xs[kk][ty * 8 + 4]);
            float4 b  = *(const float4*)(&ws[kk][tx * 4]);
            float a[8] = {a0.x, a0.y, a0.z, a0.w, a1.x, a1.y, a1.z, a1.w};
            float bb[4] = {b.x, b.y, b.z, b.w};
            #pragma unroll
            for (int i = 0; i < 8; i++)
                #pragma unroll
                for (int j = 0; j < 4; j++)
                    acc[i][j] = fmaf(a[i], bb[j], acc[i][j]);
        }
        __syncthreads();
    }

    #pragma unroll
    for (int i = 0; i < 8; i++) {
        int gr = row0 + ty * 8 + i;
        if (gr < M) {
            float4 v = make_float4(acc[i][0], acc[i][1], acc[i][2], acc[i][3]);
            *(float4*)(h + (size_t)gr * HID + tx * 4) = v;
        }
    }
}

// ---------------------------------------------------------------------------
// Scatter: one wave per item (edge or self-loop). 64 lanes x float2 = 128 cols.
// out[col] += h[row] * dis[row]*dis[col]   via fp32 global atomics.
// ---------------------------------------------------------------------------
__global__ __launch_bounds__(256) void scatter_kernel(const int* __restrict__ row,
                                                      const int* __restrict__ col,
                                                      const float* __restrict__ dis,
                                                      const float* __restrict__ h,
                                                      float* out, int E, int N) {
    int w = (blockIdx.x * 256 + threadIdx.x) >> 6;  // global wave id = item id
    int lane = threadIdx.x & 63;
    if (w >= E + N) return;
    int r, c; float nrm;
    if (w < E) {
        r = row[w]; c = col[w];
        nrm = dis[r] * dis[c];
    } else {
        r = c = w - E;
        float d = dis[r];
        nrm = d * d;
    }
    float2 v = ((const float2*)(h + (size_t)r * HID))[lane];
    float* op = out + (size_t)c * HID + lane * 2;
    atomicAdd(op,     v.x * nrm);
    atomicAdd(op + 1, v.y * nrm);
}

// ---------------------------------------------------------------------------
// Column stats: per-column sum and sum-of-squares over 50000 rows.
// 256 threads = 2 rows x 128 cols; grid-stride; block-reduce; atomic finish.
// ---------------------------------------------------------------------------
__global__ __launch_bounds__(256) void stats_kernel(const float* __restrict__ out,
                                                    float* colsum, float* colsumsq, int M) {
    int c = threadIdx.x & 127;
    int half = threadIdx.x >> 7;  // 0..1
    float s = 0.f, ss = 0.f;
    for (int r = blockIdx.x * 2 + half; r < M; r += gridDim.x * 2) {
        float v = out[(size_t)r * HID + c];
        s += v; ss += v * v;
    }
    __shared__ float sh[2][HID];
    __shared__ float shq[2][HID];
    sh[half][c] = s; shq[half][c] = ss;
    __syncthreads();
    if (half == 0) {
        s  += sh[1][c];
        ss += shq[1][c];
        atomicAdd(&colsum[c], s);
        atomicAdd(&colsumsq[c], ss);
    }
}

// ---------------------------------------------------------------------------
// BN (training stats, biased var) + ReLU, in place on out. float4 per thread.
// Note: the conv bias b cancels exactly inside BN (shifts mean equally).
// ---------------------------------------------------------------------------
__global__ __launch_bounds__(256) void bn_relu_kernel(float* __restrict__ out,
                                                      const float* __restrict__ colsum,
                                                      const float* __restrict__ colsumsq,
                                                      const float* __restrict__ gamma,
                                                      const float* __restrict__ beta, int M) {
    size_t i = (size_t)blockIdx.x * 256 + threadIdx.x;   // float4 index
    size_t total = (size_t)M * (HID / 4);
    if (i >= total) return;
    int c4 = (int)((i & (HID / 4 - 1)) * 4);
    float4 v = ((const float4*)out)[i];
    float vv[4] = {v.x, v.y, v.z, v.w};
    float res[4];
    const float invN = 1.0f / (float)M;
    #pragma unroll
    for (int j = 0; j < 4; j++) {
        int c = c4 + j;
        float mean = colsum[c] * invN;
        float var  = colsumsq[c] * invN - mean * mean;
        var = fmaxf(var, 0.0f);
        float sc = gamma[c] * rsqrtf(var + BN_EPS);
        res[j] = fmaxf(0.0f, (vv[j] - mean) * sc + beta[c]);
    }
    ((float4*)out)[i] = make_float4(res[0], res[1], res[2], res[3]);
}

// ---------------------------------------------------------------------------
extern "C" void kernel_launch(void* const* d_in, const int* in_sizes, int n_in,
                              void* d_out, int out_size, void* d_ws, size_t ws_size,
                              hipStream_t stream) {
    const float* x     = (const float*)d_in[0];
    const int*   ei    = (const int*)  d_in[1];   // [2, E] flattened: row then col
    const float* W     = (const float*)d_in[2];
    // d_in[3] = b: cancels inside BatchNorm -> unused
    const float* gamma = (const float*)d_in[4];
    const float* beta  = (const float*)d_in[5];
    float* out = (float*)d_out;

    const int* row = ei;
    const int* col = ei + N_EDGES;

    // workspace layout (floats): deg/dis[50176] | h[50000*128] | colsum[128] | colsumsq[128]
    float* ws       = (float*)d_ws;
    float* deg      = ws;
    float* h        = ws + 50176;
    float* colsum   = h + (size_t)N_NODES * HID;
    float* colsumsq = colsum + 128;

    hipMemsetAsync(d_out, 0, (size_t)out_size * sizeof(float), stream);

    init_kernel<<<(N_NODES + 255) / 256, 256, 0, stream>>>(deg, colsum, N_NODES);
    deg_kernel<<<(N_EDGES + 255) / 256, 256, 0, stream>>>(col, deg, N_EDGES);
    rsqrt_kernel<<<(N_NODES + 255) / 256, 256, 0, stream>>>(deg, N_NODES);

    gemm_kernel<<<(N_NODES + BM - 1) / BM, 256, 0, stream>>>(x, W, h, N_NODES);

    {
        int items = N_EDGES + N_NODES;          // real edges + self loops
        int blocks = (items + 3) / 4;           // 4 waves (items) per 256-thread block
        scatter_kernel<<<blocks, 256, 0, stream>>>(row, col, deg, h, out, N_EDGES, N_NODES);
    }

    stats_kernel<<<256, 256, 0, stream>>>(out, colsum, colsumsq, N_NODES);

    {
        size_t total = (size_t)N_NODES * (HID / 4);
        bn_relu_kernel<<<(int)((total + 255) / 256), 256, 0, stream>>>(out, colsum, colsumsq, gamma, beta, N_NODES);
    }
}

// Round 2
// 312.472 us; speedup vs baseline: 2.4411x; 2.4411x over previous
//
#include <hip/hip_runtime.h>

#define N_NODES 50000
#define N_EDGES 600000
#define IN_DIM  256
#define HID     128
#define BN_EPS  1e-5f

#define SCAN_BLOCKS ((N_NODES + 255) / 256)   // 196

// ---------------------------------------------------------------------------
// zero: cnt[i]=0, colsum/colsumsq (256 floats) = 0
// ---------------------------------------------------------------------------
__global__ __launch_bounds__(256) void zero_kernel(int* cnt, float* colstats, int n) {
    int i = blockIdx.x * 256 + threadIdx.x;
    if (i < n) cnt[i] = 0;
    if (i < 256) colstats[i] = 0.0f;
}

// in-degree histogram on targets
__global__ __launch_bounds__(256) void hist_kernel(const int* __restrict__ col, int* cnt, int E) {
    int i = blockIdx.x * 256 + threadIdx.x;
    if (i < E) atomicAdd(&cnt[col[i]], 1);
}

// dis[i] = rsqrt(cnt[i] + 1)   (+1 = self loop)
__global__ __launch_bounds__(256) void rsqrt_kernel(const int* __restrict__ cnt, float* dis, int n) {
    int i = blockIdx.x * 256 + threadIdx.x;
    if (i < n) dis[i] = rsqrtf((float)cnt[i] + 1.0f);
}

// ---------------------------------------------------------------------------
// 3-step exclusive scan of cnt[50000] -> rowptr[50001], cursor = rowptr copy
// ---------------------------------------------------------------------------
__global__ __launch_bounds__(256) void scan_blocksum_kernel(const int* __restrict__ cnt,
                                                            int* blocksums, int n) {
    __shared__ int s[256];
    int i = blockIdx.x * 256 + threadIdx.x;
    s[threadIdx.x] = (i < n) ? cnt[i] : 0;
    __syncthreads();
    for (int off = 128; off > 0; off >>= 1) {
        if (threadIdx.x < off) s[threadIdx.x] += s[threadIdx.x + off];
        __syncthreads();
    }
    if (threadIdx.x == 0) blocksums[blockIdx.x] = s[0];
}

__global__ __launch_bounds__(256) void scan_top_kernel(int* blocksums, int nb) {
    __shared__ int s[256];
    int t = threadIdx.x;
    int v = (t < nb) ? blocksums[t] : 0;
    s[t] = v;
    __syncthreads();
    for (int off = 1; off < 256; off <<= 1) {
        int x = 0;
        if (t >= off) x = s[t - off];
        __syncthreads();
        if (t >= off) s[t] += x;
        __syncthreads();
    }
    if (t < nb) blocksums[t] = s[t] - v;   // exclusive
}

__global__ __launch_bounds__(256) void scan_final_kernel(const int* __restrict__ cnt,
                                                         const int* __restrict__ blocksums,
                                                         int* rowptr, int* cursor, int n) {
    __shared__ int s[256];
    int t = threadIdx.x;
    int i = blockIdx.x * 256 + t;
    int v = (i < n) ? cnt[i] : 0;
    s[t] = v;
    __syncthreads();
    for (int off = 1; off < 256; off <<= 1) {
        int x = 0;
        if (t >= off) x = s[t - off];
        __syncthreads();
        if (t >= off) s[t] += x;
        __syncthreads();
    }
    if (i < n) {
        int excl = blocksums[blockIdx.x] + s[t] - v;
        rowptr[i] = excl;
        cursor[i] = excl;
    }
    if (i == n - 1) rowptr[n] = N_EDGES;
}

// scatter edges into CSR order: srcs[cursor[col]++] = row
__global__ __launch_bounds__(256) void fill_kernel(const int* __restrict__ row,
                                                   const int* __restrict__ col,
                                                   int* cursor, int* srcs, int E) {
    int i = blockIdx.x * 256 + threadIdx.x;
    if (i < E) {
        int c = col[i];
        int pos = atomicAdd(&cursor[c], 1);
        srcs[pos] = row[i];
    }
}

// ---------------------------------------------------------------------------
// GEMM: h[M,128] = x[M,256] @ W[256,128], fp32 vector ALU.
// ---------------------------------------------------------------------------
#define BM 64
#define BK 32

__global__ __launch_bounds__(256) void gemm_kernel(const float* __restrict__ x,
                                                   const float* __restrict__ W,
                                                   float* __restrict__ h, int M) {
    __shared__ float xs[BK][BM];
    __shared__ float ws[BK][HID];
    const int t = threadIdx.x;
    const int row0 = blockIdx.x * BM;
    const int tx = t & 31;
    const int ty = t >> 5;

    float acc[8][4];
    #pragma unroll
    for (int i = 0; i < 8; i++)
        #pragma unroll
        for (int j = 0; j < 4; j++) acc[i][j] = 0.0f;

    for (int k0 = 0; k0 < IN_DIM; k0 += BK) {
        #pragma unroll
        for (int l = 0; l < 2; l++) {
            int q = t + l * 256;
            int r = q >> 3, kq = q & 7;
            int gr = row0 + r;
            float4 v = make_float4(0.f, 0.f, 0.f, 0.f);
            if (gr < M) v = *(const float4*)(x + (size_t)gr * IN_DIM + k0 + kq * 4);
            xs[kq * 4 + 0][r] = v.x;
            xs[kq * 4 + 1][r] = v.y;
            xs[kq * 4 + 2][r] = v.z;
            xs[kq * 4 + 3][r] = v.w;
        }
        #pragma unroll
        for (int l = 0; l < 4; l++) {
            int q = t + l * 256;
            int kk = q >> 5, c4 = q & 31;
            *(float4*)(&ws[kk][c4 * 4]) = *(const float4*)(W + (size_t)(k0 + kk) * HID + c4 * 4);
        }
        __syncthreads();

        #pragma unroll
        for (int kk = 0; kk < BK; kk++) {
            float4 a0 = *(const float4*)(&xs[kk][ty * 8]);
            float4 a1 = *(const float4*)(&xs[kk][ty * 8 + 4]);
            float4 b  = *(const float4*)(&ws[kk][tx * 4]);
            float a[8] = {a0.x, a0.y, a0.z, a0.w, a1.x, a1.y, a1.z, a1.w};
            float bb[4] = {b.x, b.y, b.z, b.w};
            #pragma unroll
            for (int i = 0; i < 8; i++)
                #pragma unroll
                for (int j = 0; j < 4; j++)
                    acc[i][j] = fmaf(a[i], bb[j], acc[i][j]);
        }
        __syncthreads();
    }

    #pragma unroll
    for (int i = 0; i < 8; i++) {
        int gr = row0 + ty * 8 + i;
        if (gr < M) {
            float4 v = make_float4(acc[i][0], acc[i][1], acc[i][2], acc[i][3]);
            *(float4*)(h + (size_t)gr * HID + tx * 4) = v;
        }
    }
}

// ---------------------------------------------------------------------------
// Gather: one wave per target node. out[n] = dis[n]*(dis[n]*h[n] + sum dis[s]*h[s])
// 64 lanes x float2 = 128 cols. Register accumulate, single coalesced write.
// ---------------------------------------------------------------------------
__global__ __launch_bounds__(256) void gather_kernel(const int* __restrict__ rowptr,
                                                     const int* __restrict__ srcs,
                                                     const float* __restrict__ dis,
                                                     const float* __restrict__ h,
                                                     float* __restrict__ out) {
    int node = (blockIdx.x * 256 + threadIdx.x) >> 6;
    int lane = threadIdx.x & 63;
    if (node >= N_NODES) return;
    int beg = rowptr[node], end = rowptr[node + 1];
    float dn = dis[node];
    float2 v = ((const float2*)(h + (size_t)node * HID))[lane];
    float ax = v.x * dn, ay = v.y * dn;      // self-loop message (pre dn factor)

    // software-pipeline the src index / scale loads one iteration ahead
    int s_next = (beg < end) ? srcs[beg] : 0;
    for (int e = beg; e < end; e++) {
        int s = s_next;
        if (e + 1 < end) s_next = srcs[e + 1];
        float ds = dis[s];
        float2 hv = ((const float2*)(h + (size_t)s * HID))[lane];
        ax = fmaf(hv.x, ds, ax);
        ay = fmaf(hv.y, ds, ay);
    }
    ax *= dn; ay *= dn;
    ((float2*)(out + (size_t)node * HID))[lane] = make_float2(ax, ay);
}

// ---------------------------------------------------------------------------
// Column stats over out[50000,128]
// ---------------------------------------------------------------------------
__global__ __launch_bounds__(256) void stats_kernel(const float* __restrict__ out,
                                                    float* colsum, float* colsumsq, int M) {
    int c = threadIdx.x & 127;
    int half = threadIdx.x >> 7;
    float s = 0.f, ss = 0.f;
    for (int r = blockIdx.x * 2 + half; r < M; r += gridDim.x * 2) {
        float v = out[(size_t)r * HID + c];
        s += v; ss += v * v;
    }
    __shared__ float sh[2][HID];
    __shared__ float shq[2][HID];
    sh[half][c] = s; shq[half][c] = ss;
    __syncthreads();
    if (half == 0) {
        s  += sh[1][c];
        ss += shq[1][c];
        atomicAdd(&colsum[c], s);
        atomicAdd(&colsumsq[c], ss);
    }
}

// ---------------------------------------------------------------------------
// BN (training stats, biased var) + ReLU, in place. (bias b cancels in BN)
// ---------------------------------------------------------------------------
__global__ __launch_bounds__(256) void bn_relu_kernel(float* __restrict__ out,
                                                      const float* __restrict__ colsum,
                                                      const float* __restrict__ colsumsq,
                                                      const float* __restrict__ gamma,
                                                      const float* __restrict__ beta, int M) {
    size_t i = (size_t)blockIdx.x * 256 + threadIdx.x;
    size_t total = (size_t)M * (HID / 4);
    if (i >= total) return;
    int c4 = (int)((i & (HID / 4 - 1)) * 4);
    float4 v = ((const float4*)out)[i];
    float vv[4] = {v.x, v.y, v.z, v.w};
    float res[4];
    const float invN = 1.0f / (float)M;
    #pragma unroll
    for (int j = 0; j < 4; j++) {
        int c = c4 + j;
        float mean = colsum[c] * invN;
        float var  = colsumsq[c] * invN - mean * mean;
        var = fmaxf(var, 0.0f);
        float sc = gamma[c] * rsqrtf(var + BN_EPS);
        res[j] = fmaxf(0.0f, (vv[j] - mean) * sc + beta[c]);
    }
    ((float4*)out)[i] = make_float4(res[0], res[1], res[2], res[3]);
}

// ---------------------------------------------------------------------------
extern "C" void kernel_launch(void* const* d_in, const int* in_sizes, int n_in,
                              void* d_out, int out_size, void* d_ws, size_t ws_size,
                              hipStream_t stream) {
    const float* x     = (const float*)d_in[0];
    const int*   ei    = (const int*)  d_in[1];   // [2,E] flat: row(src) then col(dst)
    const float* W     = (const float*)d_in[2];
    // d_in[3] = b: cancels inside BatchNorm -> unused
    const float* gamma = (const float*)d_in[4];
    const float* beta  = (const float*)d_in[5];
    float* out = (float*)d_out;

    const int* row = ei;
    const int* col = ei + N_EDGES;

    // workspace layout (4-byte elems)
    int*   cnt       = (int*)d_ws;                         // [50000]
    float* dis       = (float*)d_ws + 50000;               // [50000]
    int*   rowptr    = (int*)d_ws + 100000;                // [50001]
    int*   cursor    = (int*)d_ws + 150016;                // [50000]
    int*   blocksums = (int*)d_ws + 200016;                // [256]
    int*   srcs      = (int*)d_ws + 200272;                // [600000]
    float* h         = (float*)d_ws + 800272;              // [50000*128]
    float* colsum    = (float*)d_ws + 7200272;             // [128]
    float* colsumsq  = (float*)d_ws + 7200400;             // [128]

    zero_kernel<<<(N_NODES + 255) / 256, 256, 0, stream>>>(cnt, colsum, N_NODES);
    hist_kernel<<<(N_EDGES + 255) / 256, 256, 0, stream>>>(col, cnt, N_EDGES);
    rsqrt_kernel<<<(N_NODES + 255) / 256, 256, 0, stream>>>(cnt, dis, N_NODES);

    scan_blocksum_kernel<<<SCAN_BLOCKS, 256, 0, stream>>>(cnt, blocksums, N_NODES);
    scan_top_kernel<<<1, 256, 0, stream>>>(blocksums, SCAN_BLOCKS);
    scan_final_kernel<<<SCAN_BLOCKS, 256, 0, stream>>>(cnt, blocksums, rowptr, cursor, N_NODES);

    fill_kernel<<<(N_EDGES + 255) / 256, 256, 0, stream>>>(row, col, cursor, srcs, N_EDGES);

    gemm_kernel<<<(N_NODES + BM - 1) / BM, 256, 0, stream>>>(x, W, h, N_NODES);

    gather_kernel<<<(N_NODES * 64 + 255) / 256, 256, 0, stream>>>(rowptr, srcs, dis, h, out);

    stats_kernel<<<256, 256, 0, stream>>>(out, colsum, colsumsq, N_NODES);

    {
        size_t total = (size_t)N_NODES * (HID / 4);
        bn_relu_kernel<<<(int)((total + 255) / 256), 256, 0, stream>>>(out, colsum, colsumsq, gamma, beta, N_NODES);
    }
}

// Round 3
// 279.187 us; speedup vs baseline: 2.7321x; 1.1192x over previous
//
#include <hip/hip_runtime.h>

#define N_NODES 50000
#define N_EDGES 600000
#define IN_DIM  256
#define HID     128
#define BN_EPS  1e-5f

#define SCAN_BLOCKS ((N_NODES + 255) / 256)   // 196

typedef __attribute__((ext_vector_type(8))) short bf16x8;   // 8 bf16 = 4 VGPRs
typedef __attribute__((ext_vector_type(4))) float f32x4;

__device__ __forceinline__ ushort f2bf(float f) {           // RNE fp32->bf16
    union { float f; uint u; } v; v.f = f;
    return (ushort)((v.u + 0x7FFFu + ((v.u >> 16) & 1u)) >> 16);
}

// ---------------------------------------------------------------------------
// zero: cnt = 0, colsum/colsumsq (256 floats) = 0
// ---------------------------------------------------------------------------
__global__ __launch_bounds__(256) void zero_kernel(int* cnt, float* colstats, int n) {
    int i = blockIdx.x * 256 + threadIdx.x;
    if (i < n) cnt[i] = 0;
    if (i < 256) colstats[i] = 0.0f;
}

// in-degree histogram on targets
__global__ __launch_bounds__(256) void hist_kernel(const int* __restrict__ col, int* cnt, int E) {
    int i = blockIdx.x * 256 + threadIdx.x;
    if (i < E) atomicAdd(&cnt[col[i]], 1);
}

// ---------------------------------------------------------------------------
// 3-step exclusive scan of cnt[50000] -> rowptr/cursor; also dis = rsqrt(cnt+1)
// ---------------------------------------------------------------------------
__global__ __launch_bounds__(256) void scan_blocksum_kernel(const int* __restrict__ cnt,
                                                            int* blocksums, int n) {
    __shared__ int s[256];
    int i = blockIdx.x * 256 + threadIdx.x;
    s[threadIdx.x] = (i < n) ? cnt[i] : 0;
    __syncthreads();
    for (int off = 128; off > 0; off >>= 1) {
        if (threadIdx.x < off) s[threadIdx.x] += s[threadIdx.x + off];
        __syncthreads();
    }
    if (threadIdx.x == 0) blocksums[blockIdx.x] = s[0];
}

__global__ __launch_bounds__(256) void scan_top_kernel(int* blocksums, int nb) {
    __shared__ int s[256];
    int t = threadIdx.x;
    int v = (t < nb) ? blocksums[t] : 0;
    s[t] = v;
    __syncthreads();
    for (int off = 1; off < 256; off <<= 1) {
        int x = 0;
        if (t >= off) x = s[t - off];
        __syncthreads();
        if (t >= off) s[t] += x;
        __syncthreads();
    }
    if (t < nb) blocksums[t] = s[t] - v;   // exclusive
}

__global__ __launch_bounds__(256) void scan_final_kernel(const int* __restrict__ cnt,
                                                         const int* __restrict__ blocksums,
                                                         int* rowptr, int* cursor,
                                                         float* dis, int n) {
    __shared__ int s[256];
    int t = threadIdx.x;
    int i = blockIdx.x * 256 + t;
    int v = (i < n) ? cnt[i] : 0;
    s[t] = v;
    __syncthreads();
    for (int off = 1; off < 256; off <<= 1) {
        int x = 0;
        if (t >= off) x = s[t - off];
        __syncthreads();
        if (t >= off) s[t] += x;
        __syncthreads();
    }
    if (i < n) {
        int excl = blocksums[blockIdx.x] + s[t] - v;
        rowptr[i] = excl;
        cursor[i] = excl;
        dis[i] = rsqrtf((float)v + 1.0f);   // +1 = self loop
    }
    if (i == n - 1) rowptr[n] = N_EDGES;
}

// W [256][128] fp32 -> Wt [128][256] bf16 (transposed). Runs AFTER scans
// because Wt overlays the dead cnt region.
__global__ __launch_bounds__(256) void prep_w_kernel(const float* __restrict__ W, ushort* Wt) {
    int i = blockIdx.x * 256 + threadIdx.x;   // 0 .. 32767
    int n = i >> 8, k = i & 255;
    Wt[n * IN_DIM + k] = f2bf(W[(size_t)k * HID + n]);
}

// scatter edges into CSR order: srcs[cursor[col]++] = row
__global__ __launch_bounds__(256) void fill_kernel(const int* __restrict__ row,
                                                   const int* __restrict__ col,
                                                   int* cursor, int* srcs, int E) {
    int i = blockIdx.x * 256 + threadIdx.x;
    if (i < E) {
        int c = col[i];
        int pos = atomicAdd(&cursor[c], 1);
        srcs[pos] = row[i];
    }
}

// ---------------------------------------------------------------------------
// GEMM via MFMA: h[M,128] = x[M,256] @ W[256,128].
// bf16 inputs (converted in staging), fp32 accumulate, fp32 h.
// Block: 256 thr = 4 waves. BM=64 (16 rows/wave), BN=128 (8 col-tiles), BK=32.
// LDS stride 40 bf16 (80 B = 20 banks) -> only free 2-way conflicts on b128.
// ---------------------------------------------------------------------------
#define LDA 40

__global__ __launch_bounds__(256) void gemm_kernel(const float* __restrict__ x,
                                                   const ushort* __restrict__ Wt,
                                                   float* __restrict__ h, int M) {
    __shared__ ushort As[64][LDA];
    __shared__ ushort Bs[128][LDA];
    const int t = threadIdx.x;
    const int row0 = blockIdx.x * 64;
    const int wave = t >> 6, lane = t & 63;
    const int lrow = lane & 15, quad = lane >> 4;

    f32x4 acc[8];
    #pragma unroll
    for (int c = 0; c < 8; c++) acc[c] = (f32x4){0.f, 0.f, 0.f, 0.f};

    const int arow = t >> 2, aq = t & 3;   // A staging: row 0..63, 8-float chunk 0..3
    const int bn = t >> 1, bh = t & 1;     // B staging: n 0..127, 16-elem half

    for (int k0 = 0; k0 < IN_DIM; k0 += 32) {
        // stage A: 64 rows x 32 k, fp32 -> bf16
        {
            int gr = row0 + arow;
            uint4 pk = make_uint4(0, 0, 0, 0);
            if (gr < M) {
                const float* src = x + (size_t)gr * IN_DIM + k0 + aq * 8;
                float4 f0 = *(const float4*)src;
                float4 f1 = *(const float4*)(src + 4);
                pk.x = f2bf(f0.x) | ((uint)f2bf(f0.y) << 16);
                pk.y = f2bf(f0.z) | ((uint)f2bf(f0.w) << 16);
                pk.z = f2bf(f1.x) | ((uint)f2bf(f1.y) << 16);
                pk.w = f2bf(f1.z) | ((uint)f2bf(f1.w) << 16);
            }
            *(uint4*)&As[arow][aq * 8] = pk;
        }
        // stage B: 128 n-rows x 32 k from Wt[n][k] (already bf16, k-contiguous)
        {
            const uint4* src = (const uint4*)(Wt + (size_t)bn * IN_DIM + k0 + bh * 16);
            *(uint4*)&Bs[bn][bh * 16]     = src[0];
            *(uint4*)&Bs[bn][bh * 16 + 8] = src[1];
        }
        __syncthreads();

        // A frag: A[m=lane&15][k=quad*8+j]; B frag: B[n=lane&15][k=quad*8+j]
        bf16x8 af = *(const bf16x8*)&As[wave * 16 + lrow][quad * 8];
        #pragma unroll
        for (int c = 0; c < 8; c++) {
            bf16x8 bfr = *(const bf16x8*)&Bs[c * 16 + lrow][quad * 8];
            acc[c] = __builtin_amdgcn_mfma_f32_16x16x32_bf16(af, bfr, acc[c], 0, 0, 0);
        }
        __syncthreads();
    }

    // epilogue: C/D layout col=lane&15, row=quad*4+reg  (verified m89/m91)
    #pragma unroll
    for (int c = 0; c < 8; c++) {
        #pragma unroll
        for (int r = 0; r < 4; r++) {
            int gr = row0 + wave * 16 + quad * 4 + r;
            if (gr < M) h[(size_t)gr * HID + c * 16 + lrow] = acc[c][r];
        }
    }
}

// ---------------------------------------------------------------------------
// Gather: one wave per target node. out[n] = dis[n]*(dis[n]*h[n] + sum dis[s]*h[s])
// ---------------------------------------------------------------------------
__global__ __launch_bounds__(256) void gather_kernel(const int* __restrict__ rowptr,
                                                     const int* __restrict__ srcs,
                                                     const float* __restrict__ dis,
                                                     const float* __restrict__ h,
                                                     float* __restrict__ out) {
    int node = (blockIdx.x * 256 + threadIdx.x) >> 6;
    int lane = threadIdx.x & 63;
    if (node >= N_NODES) return;
    int beg = rowptr[node], end = rowptr[node + 1];
    float dn = dis[node];
    float2 v = ((const float2*)(h + (size_t)node * HID))[lane];
    float ax = v.x * dn, ay = v.y * dn;      // self-loop message (pre dn factor)

    int s_next = (beg < end) ? srcs[beg] : 0;
    for (int e = beg; e < end; e++) {
        int s = s_next;
        if (e + 1 < end) s_next = srcs[e + 1];
        float ds = dis[s];
        float2 hv = ((const float2*)(h + (size_t)s * HID))[lane];
        ax = fmaf(hv.x, ds, ax);
        ay = fmaf(hv.y, ds, ay);
    }
    ax *= dn; ay *= dn;
    ((float2*)(out + (size_t)node * HID))[lane] = make_float2(ax, ay);
}

// ---------------------------------------------------------------------------
// Column stats over out[50000,128]
// ---------------------------------------------------------------------------
__global__ __launch_bounds__(256) void stats_kernel(const float* __restrict__ out,
                                                    float* colsum, float* colsumsq, int M) {
    int c = threadIdx.x & 127;
    int half = threadIdx.x >> 7;
    float s = 0.f, ss = 0.f;
    for (int r = blockIdx.x * 2 + half; r < M; r += gridDim.x * 2) {
        float v = out[(size_t)r * HID + c];
        s += v; ss += v * v;
    }
    __shared__ float sh[2][HID];
    __shared__ float shq[2][HID];
    sh[half][c] = s; shq[half][c] = ss;
    __syncthreads();
    if (half == 0) {
        s  += sh[1][c];
        ss += shq[1][c];
        atomicAdd(&colsum[c], s);
        atomicAdd(&colsumsq[c], ss);
    }
}

// ---------------------------------------------------------------------------
// BN (training stats, biased var) + ReLU, in place. (bias b cancels in BN)
// ---------------------------------------------------------------------------
__global__ __launch_bounds__(256) void bn_relu_kernel(float* __restrict__ out,
                                                      const float* __restrict__ colsum,
                                                      const float* __restrict__ colsumsq,
                                                      const float* __restrict__ gamma,
                                                      const float* __restrict__ beta, int M) {
    size_t i = (size_t)blockIdx.x * 256 + threadIdx.x;
    size_t total = (size_t)M * (HID / 4);
    if (i >= total) return;
    int c4 = (int)((i & (HID / 4 - 1)) * 4);
    float4 v = ((const float4*)out)[i];
    float vv[4] = {v.x, v.y, v.z, v.w};
    float res[4];
    const float invN = 1.0f / (float)M;
    #pragma unroll
    for (int j = 0; j < 4; j++) {
        int c = c4 + j;
        float mean = colsum[c] * invN;
        float var  = colsumsq[c] * invN - mean * mean;
        var = fmaxf(var, 0.0f);
        float sc = gamma[c] * rsqrtf(var + BN_EPS);
        res[j] = fmaxf(0.0f, (vv[j] - mean) * sc + beta[c]);
    }
    ((float4*)out)[i] = make_float4(res[0], res[1], res[2], res[3]);
}

// ---------------------------------------------------------------------------
extern "C" void kernel_launch(void* const* d_in, const int* in_sizes, int n_in,
                              void* d_out, int out_size, void* d_ws, size_t ws_size,
                              hipStream_t stream) {
    const float* x     = (const float*)d_in[0];
    const int*   ei    = (const int*)  d_in[1];   // [2,E] flat: row(src) then col(dst)
    const float* W     = (const float*)d_in[2];
    // d_in[3] = b: cancels inside BatchNorm -> unused
    const float* gamma = (const float*)d_in[4];
    const float* beta  = (const float*)d_in[5];
    float* out = (float*)d_out;

    const int* row = ei;
    const int* col = ei + N_EDGES;

    // workspace layout (4-byte elems)
    int*   cnt       = (int*)d_ws;                         // [50000] (dead after scans)
    float* dis       = (float*)d_ws + 50000;               // [50000]
    int*   rowptr    = (int*)d_ws + 100000;                // [50001]
    int*   cursor    = (int*)d_ws + 150016;                // [50000]
    int*   blocksums = (int*)d_ws + 200016;                // [256]
    int*   srcs      = (int*)d_ws + 200272;                // [600000]
    float* h         = (float*)d_ws + 800272;              // [50000*128] fp32
    float* colsum    = (float*)d_ws + 7200272;             // [128]
    float* colsumsq  = (float*)d_ws + 7200400;             // [128]
    ushort* Wt       = (ushort*)cnt;                       // [128*256] bf16, overlays cnt

    zero_kernel<<<(N_NODES + 255) / 256, 256, 0, stream>>>(cnt, colsum, N_NODES);
    hist_kernel<<<(N_EDGES + 255) / 256, 256, 0, stream>>>(col, cnt, N_EDGES);

    scan_blocksum_kernel<<<SCAN_BLOCKS, 256, 0, stream>>>(cnt, blocksums, N_NODES);
    scan_top_kernel<<<1, 256, 0, stream>>>(blocksums, SCAN_BLOCKS);
    scan_final_kernel<<<SCAN_BLOCKS, 256, 0, stream>>>(cnt, blocksums, rowptr, cursor, dis, N_NODES);

    prep_w_kernel<<<(IN_DIM * HID) / 256, 256, 0, stream>>>(W, Wt);   // cnt now dead

    fill_kernel<<<(N_EDGES + 255) / 256, 256, 0, stream>>>(row, col, cursor, srcs, N_EDGES);

    gemm_kernel<<<(N_NODES + 63) / 64, 256, 0, stream>>>(x, Wt, h, N_NODES);

    gather_kernel<<<(N_NODES * 64 + 255) / 256, 256, 0, stream>>>(rowptr, srcs, dis, h, out);

    stats_kernel<<<256, 256, 0, stream>>>(out, colsum, colsumsq, N_NODES);

    {
        size_t total = (size_t)N_NODES * (HID / 4);
        bn_relu_kernel<<<(int)((total + 255) / 256), 256, 0, stream>>>(out, colsum, colsumsq, gamma, beta, N_NODES);
    }
}

// Round 4
// 250.002 us; speedup vs baseline: 3.0510x; 1.1167x over previous
//
#include <hip/hip_runtime.h>

#define N_NODES 50000
#define N_EDGES 600000
#define IN_DIM  256
#define HID     128
#define BN_EPS  1e-5f

#define SCAN_BLOCKS ((N_NODES + 255) / 256)     // 196
#define HIST_BLOCKS ((N_EDGES + 255) / 256)     // 2344
#define PREPW_BLOCKS ((IN_DIM * HID) / 256)     // 128

typedef __attribute__((ext_vector_type(8))) short bf16x8;   // 8 bf16 = 4 VGPRs
typedef __attribute__((ext_vector_type(4))) float f32x4;

__device__ __forceinline__ ushort f2bf(float f) {           // RNE fp32->bf16
    union { float f; uint u; } v; v.f = f;
    return (ushort)((v.u + 0x7FFFu + ((v.u >> 16) & 1u)) >> 16);
}
__device__ __forceinline__ float bflo(uint u) {             // low bf16 of pair -> f32
    union { uint u; float f; } v; v.u = u << 16; return v.f;
}
__device__ __forceinline__ float bfhi(uint u) {             // high bf16 of pair -> f32
    union { uint u; float f; } v; v.u = u & 0xFFFF0000u; return v.f;
}

// ---------------------------------------------------------------------------
// zero: cnt = 0, colsum/colsumsq (256 floats) = 0
// ---------------------------------------------------------------------------
__global__ __launch_bounds__(256) void zero_kernel(int* cnt, float* colstats, int n) {
    int i = blockIdx.x * 256 + threadIdx.x;
    if (i < n) cnt[i] = 0;
    if (i < 256) colstats[i] = 0.0f;
}

// in-degree histogram on targets; trailing blocks convert W -> Wt (bf16, transposed)
__global__ __launch_bounds__(256) void hist_prepw_kernel(const int* __restrict__ col, int* cnt,
                                                         const float* __restrict__ W, ushort* Wt) {
    int b = blockIdx.x;
    if (b < HIST_BLOCKS) {
        int i = b * 256 + threadIdx.x;
        if (i < N_EDGES) atomicAdd(&cnt[col[i]], 1);
    } else {
        int i = (b - HIST_BLOCKS) * 256 + threadIdx.x;  // 0 .. 32767
        int n = i >> 8, k = i & 255;
        Wt[n * IN_DIM + k] = f2bf(W[(size_t)k * HID + n]);
    }
}

// ---------------------------------------------------------------------------
// 3-step exclusive scan of cnt[50000] -> rowptr/cursor; also dis = rsqrt(cnt+1)
// ---------------------------------------------------------------------------
__global__ __launch_bounds__(256) void scan_blocksum_kernel(const int* __restrict__ cnt,
                                                            int* blocksums, int n) {
    __shared__ int s[256];
    int i = blockIdx.x * 256 + threadIdx.x;
    s[threadIdx.x] = (i < n) ? cnt[i] : 0;
    __syncthreads();
    for (int off = 128; off > 0; off >>= 1) {
        if (threadIdx.x < off) s[threadIdx.x] += s[threadIdx.x + off];
        __syncthreads();
    }
    if (threadIdx.x == 0) blocksums[blockIdx.x] = s[0];
}

__global__ __launch_bounds__(256) void scan_top_kernel(int* blocksums, int nb) {
    __shared__ int s[256];
    int t = threadIdx.x;
    int v = (t < nb) ? blocksums[t] : 0;
    s[t] = v;
    __syncthreads();
    for (int off = 1; off < 256; off <<= 1) {
        int x = 0;
        if (t >= off) x = s[t - off];
        __syncthreads();
        if (t >= off) s[t] += x;
        __syncthreads();
    }
    if (t < nb) blocksums[t] = s[t] - v;   // exclusive
}

__global__ __launch_bounds__(256) void scan_final_kernel(const int* __restrict__ cnt,
                                                         const int* __restrict__ blocksums,
                                                         int* rowptr, int* cursor,
                                                         float* dis, int n) {
    __shared__ int s[256];
    int t = threadIdx.x;
    int i = blockIdx.x * 256 + t;
    int v = (i < n) ? cnt[i] : 0;
    s[t] = v;
    __syncthreads();
    for (int off = 1; off < 256; off <<= 1) {
        int x = 0;
        if (t >= off) x = s[t - off];
        __syncthreads();
        if (t >= off) s[t] += x;
        __syncthreads();
    }
    if (i < n) {
        int excl = blocksums[blockIdx.x] + s[t] - v;
        rowptr[i] = excl;
        cursor[i] = excl;
        dis[i] = rsqrtf((float)v + 1.0f);   // +1 = self loop
    }
    if (i == n - 1) rowptr[n] = N_EDGES;
}

// scatter edges into CSR order: srcs[cursor[col]++] = row
__global__ __launch_bounds__(256) void fill_kernel(const int* __restrict__ row,
                                                   const int* __restrict__ col,
                                                   int* cursor, int* srcs, int E) {
    int i = blockIdx.x * 256 + threadIdx.x;
    if (i < E) {
        int c = col[i];
        int pos = atomicAdd(&cursor[c], 1);
        srcs[pos] = row[i];
    }
}

// ---------------------------------------------------------------------------
// GEMM via MFMA: h[M,128](bf16) = x[M,256] @ W[256,128].
// bf16 inputs (converted in staging), fp32 accumulate, bf16 h.
// Block: 256 thr = 4 waves. BM=64 (16 rows/wave), BN=128 (8 col-tiles), BK=32.
// LDS stride 40 bf16 (80 B = 20 banks) -> only free 2-way conflicts on b128.
// ---------------------------------------------------------------------------
#define LDA 40

__global__ __launch_bounds__(256) void gemm_kernel(const float* __restrict__ x,
                                                   const ushort* __restrict__ Wt,
                                                   ushort* __restrict__ h2, int M) {
    __shared__ ushort As[64][LDA];
    __shared__ ushort Bs[128][LDA];
    const int t = threadIdx.x;
    const int row0 = blockIdx.x * 64;
    const int wave = t >> 6, lane = t & 63;
    const int lrow = lane & 15, quad = lane >> 4;

    f32x4 acc[8];
    #pragma unroll
    for (int c = 0; c < 8; c++) acc[c] = (f32x4){0.f, 0.f, 0.f, 0.f};

    const int arow = t >> 2, aq = t & 3;   // A staging: row 0..63, 8-float chunk 0..3
    const int bn = t >> 1, bh = t & 1;     // B staging: n 0..127, 16-elem half

    for (int k0 = 0; k0 < IN_DIM; k0 += 32) {
        // stage A: 64 rows x 32 k, fp32 -> bf16
        {
            int gr = row0 + arow;
            uint4 pk = make_uint4(0, 0, 0, 0);
            if (gr < M) {
                const float* src = x + (size_t)gr * IN_DIM + k0 + aq * 8;
                float4 f0 = *(const float4*)src;
                float4 f1 = *(const float4*)(src + 4);
                pk.x = f2bf(f0.x) | ((uint)f2bf(f0.y) << 16);
                pk.y = f2bf(f0.z) | ((uint)f2bf(f0.w) << 16);
                pk.z = f2bf(f1.x) | ((uint)f2bf(f1.y) << 16);
                pk.w = f2bf(f1.z) | ((uint)f2bf(f1.w) << 16);
            }
            *(uint4*)&As[arow][aq * 8] = pk;
        }
        // stage B: 128 n-rows x 32 k from Wt[n][k] (already bf16, k-contiguous)
        {
            const uint4* src = (const uint4*)(Wt + (size_t)bn * IN_DIM + k0 + bh * 16);
            *(uint4*)&Bs[bn][bh * 16]     = src[0];
            *(uint4*)&Bs[bn][bh * 16 + 8] = src[1];
        }
        __syncthreads();

        // A frag: A[m=lane&15][k=quad*8+j]; B frag: B[n=lane&15][k=quad*8+j]
        bf16x8 af = *(const bf16x8*)&As[wave * 16 + lrow][quad * 8];
        #pragma unroll
        for (int c = 0; c < 8; c++) {
            bf16x8 bfr = *(const bf16x8*)&Bs[c * 16 + lrow][quad * 8];
            acc[c] = __builtin_amdgcn_mfma_f32_16x16x32_bf16(af, bfr, acc[c], 0, 0, 0);
        }
        __syncthreads();
    }

    // epilogue: C/D layout col=lane&15, row=quad*4+reg; store bf16
    #pragma unroll
    for (int c = 0; c < 8; c++) {
        #pragma unroll
        for (int r = 0; r < 4; r++) {
            int gr = row0 + wave * 16 + quad * 4 + r;
            if (gr < M) h2[(size_t)gr * HID + c * 16 + lrow] = f2bf(acc[c][r]);
        }
    }
}

// ---------------------------------------------------------------------------
// Gather + fused column stats. Grid-stride over nodes, one wave per node.
// h rows are bf16: lane loads one uint = 2 bf16 (cols 2*lane, 2*lane+1).
// out[n] = dis[n]*(dis[n]*h[n] + sum dis[s]*h[s]); per-block stat reduce.
// ---------------------------------------------------------------------------
#define GATHER_BLOCKS 1024

__global__ __launch_bounds__(256) void gather_kernel(const int* __restrict__ rowptr,
                                                     const int* __restrict__ srcs,
                                                     const float* __restrict__ dis,
                                                     const uint* __restrict__ h2,   // 64 uints/row
                                                     float* __restrict__ out,
                                                     float* colsum, float* colsumsq) {
    const int wave = threadIdx.x >> 6, lane = threadIdx.x & 63;
    float s0 = 0.f, s1 = 0.f, q0 = 0.f, q1 = 0.f;

    for (int node = blockIdx.x * 4 + wave; node < N_NODES; node += GATHER_BLOCKS * 4) {
        int beg = rowptr[node], end = rowptr[node + 1];
        float dn = dis[node];
        uint u = h2[(size_t)node * 64 + lane];
        float ax = bflo(u) * dn, ay = bfhi(u) * dn;    // self-loop (pre dn factor)

        int e = beg;
        for (; e + 4 <= end; e += 4) {                 // 4 independent gathers in flight
            int sa = srcs[e], sb = srcs[e + 1], sc = srcs[e + 2], sd = srcs[e + 3];
            uint ua = h2[(size_t)sa * 64 + lane];
            uint ub = h2[(size_t)sb * 64 + lane];
            uint uc = h2[(size_t)sc * 64 + lane];
            uint ud = h2[(size_t)sd * 64 + lane];
            float da = dis[sa], db = dis[sb], dc = dis[sc], dd = dis[sd];
            ax = fmaf(bflo(ua), da, ax); ay = fmaf(bfhi(ua), da, ay);
            ax = fmaf(bflo(ub), db, ax); ay = fmaf(bfhi(ub), db, ay);
            ax = fmaf(bflo(uc), dc, ax); ay = fmaf(bfhi(uc), dc, ay);
            ax = fmaf(bflo(ud), dd, ax); ay = fmaf(bfhi(ud), dd, ay);
        }
        for (; e < end; e++) {
            int s = srcs[e];
            uint uv = h2[(size_t)s * 64 + lane];
            float ds = dis[s];
            ax = fmaf(bflo(uv), ds, ax); ay = fmaf(bfhi(uv), ds, ay);
        }
        ax *= dn; ay *= dn;
        ((float2*)(out + (size_t)node * HID))[lane] = make_float2(ax, ay);
        s0 += ax; s1 += ay;
        q0 = fmaf(ax, ax, q0); q1 = fmaf(ay, ay, q1);
    }

    // block-level stat reduction: cols 2*lane(+1) per lane, 4 waves
    __shared__ float rs[4][HID];
    __shared__ float rq[4][HID];
    rs[wave][lane * 2] = s0; rs[wave][lane * 2 + 1] = s1;
    rq[wave][lane * 2] = q0; rq[wave][lane * 2 + 1] = q1;
    __syncthreads();
    int t = threadIdx.x;
    if (t < HID) {
        float s = rs[0][t] + rs[1][t] + rs[2][t] + rs[3][t];
        float q = rq[0][t] + rq[1][t] + rq[2][t] + rq[3][t];
        atomicAdd(&colsum[t], s);
        atomicAdd(&colsumsq[t], q);
    }
}

// ---------------------------------------------------------------------------
// BN (training stats, biased var) + ReLU, in place. (bias b cancels in BN)
// ---------------------------------------------------------------------------
__global__ __launch_bounds__(256) void bn_relu_kernel(float* __restrict__ out,
                                                      const float* __restrict__ colsum,
                                                      const float* __restrict__ colsumsq,
                                                      const float* __restrict__ gamma,
                                                      const float* __restrict__ beta, int M) {
    size_t i = (size_t)blockIdx.x * 256 + threadIdx.x;
    size_t total = (size_t)M * (HID / 4);
    if (i >= total) return;
    int c4 = (int)((i & (HID / 4 - 1)) * 4);
    float4 v = ((const float4*)out)[i];
    float vv[4] = {v.x, v.y, v.z, v.w};
    float res[4];
    const float invN = 1.0f / (float)M;
    #pragma unroll
    for (int j = 0; j < 4; j++) {
        int c = c4 + j;
        float mean = colsum[c] * invN;
        float var  = colsumsq[c] * invN - mean * mean;
        var = fmaxf(var, 0.0f);
        float sc = gamma[c] * rsqrtf(var + BN_EPS);
        res[j] = fmaxf(0.0f, (vv[j] - mean) * sc + beta[c]);
    }
    ((float4*)out)[i] = make_float4(res[0], res[1], res[2], res[3]);
}

// ---------------------------------------------------------------------------
extern "C" void kernel_launch(void* const* d_in, const int* in_sizes, int n_in,
                              void* d_out, int out_size, void* d_ws, size_t ws_size,
                              hipStream_t stream) {
    const float* x     = (const float*)d_in[0];
    const int*   ei    = (const int*)  d_in[1];   // [2,E] flat: row(src) then col(dst)
    const float* W     = (const float*)d_in[2];
    // d_in[3] = b: cancels inside BatchNorm -> unused
    const float* gamma = (const float*)d_in[4];
    const float* beta  = (const float*)d_in[5];
    float* out = (float*)d_out;

    const int* row = ei;
    const int* col = ei + N_EDGES;

    // workspace layout (4-byte words)
    int*    cnt       = (int*)d_ws;                        // [50000]
    float*  dis       = (float*)d_ws + 50000;              // [50000]
    int*    rowptr    = (int*)d_ws + 100000;               // [50001]
    int*    cursor    = (int*)d_ws + 150016;               // [50000]
    int*    blocksums = (int*)d_ws + 200016;               // [256]
    int*    srcs      = (int*)d_ws + 200272;               // [600000]
    ushort* Wt        = (ushort*)((int*)d_ws + 800272);    // [128*256] bf16 (16384 words)
    ushort* h2        = (ushort*)((int*)d_ws + 816656);    // [50000*128] bf16 (3.2M words)
    float*  colsum    = (float*)d_ws + 4016656;            // [128]
    float*  colsumsq  = (float*)d_ws + 4016784;            // [128]

    zero_kernel<<<(N_NODES + 255) / 256, 256, 0, stream>>>(cnt, colsum, N_NODES);

    hist_prepw_kernel<<<HIST_BLOCKS + PREPW_BLOCKS, 256, 0, stream>>>(col, cnt, W, Wt);

    scan_blocksum_kernel<<<SCAN_BLOCKS, 256, 0, stream>>>(cnt, blocksums, N_NODES);
    scan_top_kernel<<<1, 256, 0, stream>>>(blocksums, SCAN_BLOCKS);
    scan_final_kernel<<<SCAN_BLOCKS, 256, 0, stream>>>(cnt, blocksums, rowptr, cursor, dis, N_NODES);

    fill_kernel<<<HIST_BLOCKS, 256, 0, stream>>>(row, col, cursor, srcs, N_EDGES);

    gemm_kernel<<<(N_NODES + 63) / 64, 256, 0, stream>>>(x, Wt, h2, N_NODES);

    gather_kernel<<<GATHER_BLOCKS, 256, 0, stream>>>(rowptr, srcs, dis, (const uint*)h2, out,
                                                     colsum, colsumsq);

    {
        size_t total = (size_t)N_NODES * (HID / 4);
        bn_relu_kernel<<<(int)((total + 255) / 256), 256, 0, stream>>>(out, colsum, colsumsq, gamma, beta, N_NODES);
    }
}